// Round 5
// baseline (177.844 us; speedup 1.0000x reference)
//
#include <hip/hip_runtime.h>

// VectorQuantizer gather: out[b][d][n] = embedding[indices[b][n]][d]
// B=32, N=4096, K=1024, D=256, fp32 out = 128 MiB -> write-BW bound (~20us floor).
//
// History:
//  R1 global float4 gather + scalar stores: ~62us. L2 write-allocate from the
//     streaming stores churned the 32MiB L2 / write path (T1).
//  R2 LDS-gather: ~85us, reverted.
//  R4 DIAGNOSTIC (rep=4, nt-stores + float2 stores): ~80us for 4 reps = ~20us/rep
//     = ~6.4 TB/s, matching the harness fill's own rate -> write floor reached.
//     __builtin_nontemporal_store (bypasses L2 allocate) is the decisive fix;
//     gathers on the L2-resident 1MiB embedding hide under the store drain.
//
// Structure: 1024 blocks x 512 threads (32 waves/CU).
//  block <-> (b, 128-n tile); lane l <-> n-pair (n0+2l, +1); wave w: d-chunks 8i+w
//  (waves 0-3 share 64B line 2i of each embedding row, waves 4-7 line 2i+1).
//  Per thread: 2 embedding rows; per iter: 2 float4 gathers, 4 nt float2 stores
//  (64 lanes x 8B = 512B contiguous per wave store instruction).

#define VQ_B 32
#define VQ_N 4096
#define VQ_D 256

typedef float vf2 __attribute__((ext_vector_type(2)));

__global__ __launch_bounds__(512, 8) void vq_gather2_kernel(
    const int* __restrict__ indices,
    const float* __restrict__ embedding,
    float* __restrict__ out)
{
    const int b  = blockIdx.x >> 5;          // 0..31
    const int n0 = (blockIdx.x & 31) << 7;   // 128-n tile base
    const int t  = threadIdx.x;
    const int w  = t >> 6;                   // wave 0..7 -> d-chunk phase
    const int l  = t & 63;                   // lane -> n-pair

    const int nA = n0 + 2 * l;
    const int2 id2 = *(const int2*)(indices + b * VQ_N + nA);

    const float4* __restrict__ rowA = (const float4*)(embedding + id2.x * VQ_D);
    const float4* __restrict__ rowB = (const float4*)(embedding + id2.y * VQ_D);

    float* __restrict__ outb = out + b * (VQ_D * VQ_N) + n0 + 2 * l;

    #pragma unroll
    for (int i = 0; i < 8; ++i) {
        const int c = i * 8 + w;             // float4 chunk 0..63 of the row
        const float4 va = rowA[c];
        const float4 vb = rowB[c];
        const int d = c << 2;
        vf2 s0 = {va.x, vb.x};
        vf2 s1 = {va.y, vb.y};
        vf2 s2 = {va.z, vb.z};
        vf2 s3 = {va.w, vb.w};
        __builtin_nontemporal_store(s0, (vf2*)(outb + (d + 0) * VQ_N));
        __builtin_nontemporal_store(s1, (vf2*)(outb + (d + 1) * VQ_N));
        __builtin_nontemporal_store(s2, (vf2*)(outb + (d + 2) * VQ_N));
        __builtin_nontemporal_store(s3, (vf2*)(outb + (d + 3) * VQ_N));
    }
}

extern "C" void kernel_launch(void* const* d_in, const int* in_sizes, int n_in,
                              void* d_out, int out_size, void* d_ws, size_t ws_size,
                              hipStream_t stream) {
    const int*   indices   = (const int*)d_in[0];    // (32,1,4096) int32
    const float* embedding = (const float*)d_in[1];  // (1024,256) fp32
    float* out = (float*)d_out;                      // (32,256,64,64) fp32

    vq_gather2_kernel<<<dim3(VQ_B * (VQ_N / 128)), dim3(512), 0, stream>>>(
        indices, embedding, out);
}